// Round 6
// baseline (107.531 us; speedup 1.0000x reference)
//
#include <hip/hip_runtime.h>
#include <math.h>

#define BB 4
#define CI 64
#define CO 64
#define HH 96
#define WW 96
#define HW (HH*WW)      // 9216
#define K2 9
#define TPX 16          // px per fused block
#define NTT (HW/TPX)    // 576 tiles per batch (fused)
#define NTP 288         // 32-px tiles per batch (prep)
#define PADC 1

typedef __attribute__((ext_vector_type(8))) short short8;
typedef __attribute__((ext_vector_type(4))) float float4v;

// ws layout:
//   xT  : BB*HW*64 ushort  (pixel-major bf16 x)
//   Wf  : 18*64*32 ushort  (MFMA A-frag packed main weights)
//   MWf : 18*16*32 ushort  (MFMA A-frag packed mask weights, rows 9..15 = 0)
#define XT_USHORTS ((size_t)BB*HW*64)
#define WF_USHORTS (18*64*32)
#define MWF_USHORTS (18*16*32)

__device__ __forceinline__ float bf2f(short s) {
    return __uint_as_float(((unsigned int)(unsigned short)s) << 16);
}
__device__ __forceinline__ short f2bf(float f) {
    unsigned int u = __float_as_uint(f);
    u = (u + 0x7fffu + ((u >> 16) & 1u)) >> 16;   // RNE
    return (short)u;
}

// XCD swizzle (hw dispatch ~ bid%8 -> XCD): XCD g serves only batch g&3 so its
// 4MB L2 caches that batch's 1.18MB xT. [R3: FETCH 15->4MB verified]
__device__ __forceinline__ void unswz16(int bid, int* b, int* tile) {
    int g = bid & 7, r = bid >> 3;
    *b = g & 3;
    *tile = (g >> 2) * 288 + r;         // [0,576)
}
__device__ __forceinline__ void unswz32(int bid, int* b, int* tile) {
    int g = bid & 7, r = bid >> 3;
    *b = g & 3;
    *tile = (g >> 2) * 144 + r;         // [0,288)
}

// ---------------- prep: x transpose->bf16 (1152 blocks) + weight pack (360) ---
#define PBASE (BB*NTP)   // 1152
__global__ __launch_bounds__(256) void prep_kernel(const float* __restrict__ x,
                                                   const float* __restrict__ wgt,
                                                   const float* __restrict__ mw,
                                                   unsigned short* __restrict__ xT,
                                                   unsigned short* __restrict__ Wf,
                                                   unsigned short* __restrict__ MWf) {
    __shared__ unsigned short ts[32][72];
    int t = threadIdx.x;
    if (blockIdx.x < PBASE) {
        int b, tl; unswz32(blockIdx.x, &b, &tl);
        int p0 = tl * 32;
        const float* xb = x + (size_t)b * CI * HW + p0;
        int c0 = t >> 3, pq = t & 7;
        #pragma unroll
        for (int i = 0; i < 2; i++) {
            int c = c0 + i * 32;
            float4v v = *(const float4v*)(xb + (size_t)c * HW + pq * 4);
            ts[pq * 4 + 0][c] = (unsigned short)f2bf(v[0]);
            ts[pq * 4 + 1][c] = (unsigned short)f2bf(v[1]);
            ts[pq * 4 + 2][c] = (unsigned short)f2bf(v[2]);
            ts[pq * 4 + 3][c] = (unsigned short)f2bf(v[3]);
        }
        __syncthreads();
        int px = t >> 3, cq = t & 7;
        unsigned short* xo = xT + ((size_t)b * HW + p0 + px) * 64 + cq * 8;
        *(short8*)xo = *(const short8*)&ts[px][cq * 8];
    } else {
        int i = (blockIdx.x - PBASE) * 256 + t;
        if (i < WF_USHORTS) {
            int frag = i >> 11;
            int o = (i >> 5) & 63;
            int tt = i & 31;
            int k = frag >> 1, cc = frag & 1;
            int c = cc * 32 + tt;
            Wf[i] = (unsigned short)f2bf(wgt[o * 576 + c * 9 + k]);
        } else if (i < WF_USHORTS + MWF_USHORTS) {
            int e = i - WF_USHORTS;
            int frag = e >> 9;
            int m = (e >> 5) & 15;
            int tt = e & 31;
            int q = frag >> 1, cc = frag & 1;
            int c = cc * 32 + tt;
            MWf[e] = (m < 9) ? (unsigned short)f2bf(mw[m * 576 + c * 9 + q]) : 0;
        }
    }
}

// ---------------- fused: mask conv + deform sample + GEMM --------------------
// Block = 4 waves over ONE 16-px tile: wave (ch = wv&1 c-half, tg = wv>>1
// tap-group {0..4}/{5..8}). launch_bounds(256,4): VGPR cap 128 so ALL of a
// wave's gathers can be in flight at once (R5's cap of 36 serialized them).
__global__ __launch_bounds__(256, 4) void fused_kernel(const float* __restrict__ off,
                                                       const float* __restrict__ mbias,
                                                       const unsigned short* __restrict__ xT,
                                                       const unsigned short* __restrict__ Wf,
                                                       const unsigned short* __restrict__ MWf,
                                                       float* __restrict__ out) {
    __shared__ float s_mred[2][2][K2][TPX];   // [ch][tg][tap][px]
    __shared__ int   s_idx[K2][4][TPX];
    __shared__ float s_w[K2][4][TPX];
    __shared__ float s_part[3][16][64];       // [wave-1][o-frag j][lane]

    int t = threadIdx.x;
    int lane = t & 63, wv = t >> 6;
    int ch = wv & 1, tg = wv >> 1;
    int n = lane & 15, quad = lane >> 4;
    int b, tl; unswz16(blockIdx.x, &b, &tl);
    int p0 = tl * TPX;
    int p = p0 + n;
    int h = p / WW, wc = p % WW;
    const unsigned short* xTb = xT + (size_t)b * HW * 64;
    int cbase = ch * 32 + quad * 8;

    // ---- phase A: mask-conv partials via MFMA, loads hoisted ----
    {
        float4v macc = {0.f, 0.f, 0.f, 0.f};
#define PHASE_A(QB, QE)                                                          \
        {                                                                        \
        short8 bf[QE - QB];                                                      \
        _Pragma("unroll")                                                        \
        for (int qq = 0; qq < QE - QB; qq++) {                                   \
            int q = QB + qq;                                                     \
            int hh = h + q / 3 - 1, ww2 = wc + q % 3 - 1;                        \
            bool valid = (hh >= 0) && (hh < HH) && (ww2 >= 0) && (ww2 < WW);     \
            int nidx = valid ? (hh * WW + ww2) : 0;                              \
            short8 tmp = {0, 0, 0, 0, 0, 0, 0, 0};                               \
            if (valid) tmp = *(const short8*)(xTb + (size_t)nidx * 64 + cbase);  \
            bf[qq] = tmp;                                                        \
        }                                                                        \
        _Pragma("unroll")                                                        \
        for (int qq = 0; qq < QE - QB; qq++) {                                   \
            int q = QB + qq;                                                     \
            short8 afrag = *(const short8*)(MWf +                                \
                ((size_t)((q * 2 + ch) * 16 + n)) * 32 + quad * 8);              \
            macc = __builtin_amdgcn_mfma_f32_16x16x32_bf16(afrag, bf[qq], macc, 0, 0, 0); \
        }                                                                        \
        }
        if (tg == 0) { PHASE_A(0, 5) } else { PHASE_A(5, 9) }
        #pragma unroll
        for (int r = 0; r < 4; r++) {
            int row = quad * 4 + r;
            if (row < 9) s_mred[ch][tg][row][n] = macc[r];
        }
    }
    __syncthreads();

    // ---- phase B: sampling metadata (one thread per (tap,px)) ----
    if (t < K2 * TPX) {
        int k = t >> 4, pe = t & 15;
        int pp = p0 + pe;
        int hh0 = pp / WW, ww0 = pp % WW;
        int ky = k / 3, kx = k % 3;
        float oy = off[((size_t)b * 2 * K2 + 2 * k) * HW + pp];
        float ox = off[((size_t)b * 2 * K2 + 2 * k + 1) * HW + pp];
        float s = s_mred[0][0][k][pe] + s_mred[0][1][k][pe] +
                  s_mred[1][0][k][pe] + s_mred[1][1][k][pe] + mbias[k];
        float m = 1.f / (1.f + expf(-s));
        float py = (float)(hh0 - PADC + ky) + oy;
        float pxf = (float)(ww0 - PADC + kx) + ox;
        float y0f = floorf(py), x0f = floorf(pxf);
        float wy = py - y0f, wx = pxf - x0f;
        int y0 = (int)y0f, x0 = (int)x0f;
        int y1 = y0 + 1, x1 = x0 + 1;
        int y0c = min(max(y0, 0), HH - 1), y1c = min(max(y1, 0), HH - 1);
        int x0c = min(max(x0, 0), WW - 1), x1c = min(max(x1, 0), WW - 1);
        bool vy0 = (y0 >= 0) && (y0 < HH), vy1 = (y1 >= 0) && (y1 < HH);
        bool vx0 = (x0 >= 0) && (x0 < WW), vx1 = (x1 >= 0) && (x1 < WW);
        float w00 = (1.f - wy) * (1.f - wx) * m; if (!(vy0 && vx0)) w00 = 0.f;
        float w01 = (1.f - wy) * wx * m;         if (!(vy0 && vx1)) w01 = 0.f;
        float w10 = wy * (1.f - wx) * m;         if (!(vy1 && vx0)) w10 = 0.f;
        float w11 = wy * wx * m;                 if (!(vy1 && vx1)) w11 = 0.f;
        s_idx[k][0][pe] = y0c * WW + x0c;
        s_idx[k][1][pe] = y0c * WW + x1c;
        s_idx[k][2][pe] = y1c * WW + x0c;
        s_idx[k][3][pe] = y1c * WW + x1c;
        s_w[k][0][pe] = w00; s_w[k][1][pe] = w01;
        s_w[k][2][pe] = w10; s_w[k][3][pe] = w11;
    }
    __syncthreads();

    // ---- phase C: ALL gathers issued up front, then blend + MFMA ----
    float4v acc0 = {0.f, 0.f, 0.f, 0.f};
    float4v acc1 = {0.f, 0.f, 0.f, 0.f};
    float4v acc2 = {0.f, 0.f, 0.f, 0.f};
    float4v acc3 = {0.f, 0.f, 0.f, 0.f};
    const unsigned short* xq = xTb + cbase;

#define PHASE_C(KB, KE)                                                          \
    {                                                                            \
    short8 U[KE - KB][4];                                                        \
    _Pragma("unroll")                                                            \
    for (int kk = 0; kk < KE - KB; kk++) {                                       \
        int k = KB + kk;                                                         \
        U[kk][0] = *(const short8*)(xq + (size_t)s_idx[k][0][n] * 64);           \
        U[kk][1] = *(const short8*)(xq + (size_t)s_idx[k][1][n] * 64);           \
        U[kk][2] = *(const short8*)(xq + (size_t)s_idx[k][2][n] * 64);           \
        U[kk][3] = *(const short8*)(xq + (size_t)s_idx[k][3][n] * 64);           \
    }                                                                            \
    _Pragma("unroll")                                                            \
    for (int kk = 0; kk < KE - KB; kk++) {                                       \
        int k = KB + kk;                                                         \
        float w0 = s_w[k][0][n], w1 = s_w[k][1][n];                              \
        float w2 = s_w[k][2][n], w3 = s_w[k][3][n];                              \
        short8 bfrag;                                                            \
        _Pragma("unroll")                                                        \
        for (int j = 0; j < 8; j++) {                                            \
            float v = bf2f(U[kk][0][j]) * w0 + bf2f(U[kk][1][j]) * w1 +          \
                      bf2f(U[kk][2][j]) * w2 + bf2f(U[kk][3][j]) * w3;           \
            bfrag[j] = f2bf(v);                                                  \
        }                                                                        \
        const unsigned short* wp = Wf + (size_t)((k * 2 + ch) * 64) * 32 + quad * 8; \
        short8 a0 = *(const short8*)(wp + (0 * 16 + n) * 32);                    \
        short8 a1 = *(const short8*)(wp + (1 * 16 + n) * 32);                    \
        short8 a2 = *(const short8*)(wp + (2 * 16 + n) * 32);                    \
        short8 a3 = *(const short8*)(wp + (3 * 16 + n) * 32);                    \
        acc0 = __builtin_amdgcn_mfma_f32_16x16x32_bf16(a0, bfrag, acc0, 0, 0, 0);\
        acc1 = __builtin_amdgcn_mfma_f32_16x16x32_bf16(a1, bfrag, acc1, 0, 0, 0);\
        acc2 = __builtin_amdgcn_mfma_f32_16x16x32_bf16(a2, bfrag, acc2, 0, 0, 0);\
        acc3 = __builtin_amdgcn_mfma_f32_16x16x32_bf16(a3, bfrag, acc3, 0, 0, 0);\
    }                                                                            \
    }
    if (tg == 0) { PHASE_C(0, 5) } else { PHASE_C(5, 9) }

    // ---- cross-wave reduce (4 partials) + epilogue ----
    if (wv != 0) {
        #pragma unroll
        for (int r = 0; r < 4; r++) {
            s_part[wv - 1][0 * 4 + r][lane] = acc0[r];
            s_part[wv - 1][1 * 4 + r][lane] = acc1[r];
            s_part[wv - 1][2 * 4 + r][lane] = acc2[r];
            s_part[wv - 1][3 * 4 + r][lane] = acc3[r];
        }
    }
    __syncthreads();
    if (wv == 0) {
        float* ob = out + (size_t)b * CO * HW + p0 + n;
        #pragma unroll
        for (int r = 0; r < 4; r++) {
            int j0 = 0 * 4 + r, j1 = 1 * 4 + r, j2 = 2 * 4 + r, j3 = 3 * 4 + r;
            ob[(size_t)(0 * 16 + quad * 4 + r) * HW] =
                acc0[r] + s_part[0][j0][lane] + s_part[1][j0][lane] + s_part[2][j0][lane];
            ob[(size_t)(1 * 16 + quad * 4 + r) * HW] =
                acc1[r] + s_part[0][j1][lane] + s_part[1][j1][lane] + s_part[2][j1][lane];
            ob[(size_t)(2 * 16 + quad * 4 + r) * HW] =
                acc2[r] + s_part[0][j2][lane] + s_part[1][j2][lane] + s_part[2][j2][lane];
            ob[(size_t)(3 * 16 + quad * 4 + r) * HW] =
                acc3[r] + s_part[0][j3][lane] + s_part[1][j3][lane] + s_part[2][j3][lane];
        }
    }
}

extern "C" void kernel_launch(void* const* d_in, const int* in_sizes, int n_in,
                              void* d_out, int out_size, void* d_ws, size_t ws_size,
                              hipStream_t stream) {
    const float* x   = (const float*)d_in[0];
    const float* off = (const float*)d_in[1];
    const float* wgt = (const float*)d_in[2];
    const float* mw  = (const float*)d_in[3];
    const float* mb  = (const float*)d_in[4];
    float* out = (float*)d_out;

    unsigned short* xT  = (unsigned short*)d_ws;
    unsigned short* Wf  = xT + XT_USHORTS;
    unsigned short* MWf = Wf + WF_USHORTS;

    int prep_grid = PBASE + (WF_USHORTS + MWF_USHORTS + 255) / 256;   // 1152 + 360
    hipLaunchKernelGGL(prep_kernel, dim3(prep_grid), dim3(256), 0, stream,
                       x, wgt, mw, xT, Wf, MWf);
    hipLaunchKernelGGL(fused_kernel, dim3(BB * NTT), dim3(256), 0, stream,
                       off, mb, xT, Wf, MWf, out);
}

// Round 7
// 103.541 us; speedup vs baseline: 1.0385x; 1.0385x over previous
//
#include <hip/hip_runtime.h>
#include <math.h>

#define BB 4
#define CI 64
#define CO 64
#define HH 96
#define WW 96
#define HW (HH*WW)      // 9216
#define K2 9
#define TPX 16          // px per tile
#define NTT (HW/TPX)    // 576 tiles per batch
#define NTILES (BB*NTT) // 2304
#define GRID 512        // persistent blocks: 2/CU, each ~4.5 tiles
#define NTP 288
#define PADC 1

typedef __attribute__((ext_vector_type(8))) short short8;
typedef __attribute__((ext_vector_type(4))) float float4v;

#define XT_USHORTS ((size_t)BB*HW*64)
#define WF_USHORTS (18*64*32)
#define MWF_USHORTS (18*16*32)

__device__ __forceinline__ float bf2f(short s) {
    return __uint_as_float(((unsigned int)(unsigned short)s) << 16);
}
__device__ __forceinline__ short f2bf(float f) {
    unsigned int u = __float_as_uint(f);
    u = (u + 0x7fffu + ((u >> 16) & 1u)) >> 16;   // RNE
    return (short)u;
}

// XCD swizzle: XCD g serves only batch g&3 (xT slice 1.18MB fits 4MB L2).
// [R3: FETCH 15->4MB verified]. Stride-512 tile loop preserves g (512%8==0).
__device__ __forceinline__ void unswz16(int tt, int* b, int* tile) {
    int g = tt & 7, r = tt >> 3;        // r in 0..287
    *b = g & 3;
    *tile = (g >> 2) * 288 + r;         // [0,576)
}
__device__ __forceinline__ void unswz32(int bid, int* b, int* tile) {
    int g = bid & 7, r = bid >> 3;
    *b = g & 3;
    *tile = (g >> 2) * 144 + r;         // [0,288)
}

// ---------------- prep: x transpose->bf16 (1152 blocks) + weight pack (360) ---
#define PBASE (BB*NTP)   // 1152
__global__ __launch_bounds__(256) void prep_kernel(const float* __restrict__ x,
                                                   const float* __restrict__ wgt,
                                                   const float* __restrict__ mw,
                                                   unsigned short* __restrict__ xT,
                                                   unsigned short* __restrict__ Wf,
                                                   unsigned short* __restrict__ MWf) {
    __shared__ unsigned short ts[32][72];
    int t = threadIdx.x;
    if (blockIdx.x < PBASE) {
        int b, tl; unswz32(blockIdx.x, &b, &tl);
        int p0 = tl * 32;
        const float* xb = x + (size_t)b * CI * HW + p0;
        int c0 = t >> 3, pq = t & 7;
        #pragma unroll
        for (int i = 0; i < 2; i++) {
            int c = c0 + i * 32;
            float4v v = *(const float4v*)(xb + (size_t)c * HW + pq * 4);
            ts[pq * 4 + 0][c] = (unsigned short)f2bf(v[0]);
            ts[pq * 4 + 1][c] = (unsigned short)f2bf(v[1]);
            ts[pq * 4 + 2][c] = (unsigned short)f2bf(v[2]);
            ts[pq * 4 + 3][c] = (unsigned short)f2bf(v[3]);
        }
        __syncthreads();
        int px = t >> 3, cq = t & 7;
        unsigned short* xo = xT + ((size_t)b * HW + p0 + px) * 64 + cq * 8;
        *(short8*)xo = *(const short8*)&ts[px][cq * 8];
    } else {
        int i = (blockIdx.x - PBASE) * 256 + t;
        if (i < WF_USHORTS) {
            int frag = i >> 11;
            int o = (i >> 5) & 63;
            int tt = i & 31;
            int k = frag >> 1, cc = frag & 1;
            int c = cc * 32 + tt;
            Wf[i] = (unsigned short)f2bf(wgt[o * 576 + c * 9 + k]);
        } else if (i < WF_USHORTS + MWF_USHORTS) {
            int e = i - WF_USHORTS;
            int frag = e >> 9;
            int m = (e >> 5) & 15;
            int tt = e & 31;
            int q = frag >> 1, cc = frag & 1;
            int c = cc * 32 + tt;
            MWf[e] = (m < 9) ? (unsigned short)f2bf(mw[m * 576 + c * 9 + q]) : 0;
        }
    }
}

// ---------------- fused: persistent blocks, register-resident weights ---------
struct SmemT {
    float mred[2][2][K2][TPX];   // [ch][tg][tap][px]
    int   idx[K2][4][TPX];
    float w[K2][4][TPX];
    float part[3][16][64];       // [wave-1][o-frag j][lane]
};

template<int KB, int KE>
__device__ __forceinline__ void tile_work(SmemT& sm, int t, int wv, int ch,
                                          int tg, int n, int quad,
                                          const float* __restrict__ off,
                                          const float* __restrict__ mbias,
                                          const unsigned short* __restrict__ xT,
                                          const unsigned short* __restrict__ Wf,
                                          const unsigned short* __restrict__ MWf,
                                          float* __restrict__ out, int bid) {
    constexpr int NK = KE - KB;
    int lane = t & 63;

    // ---- one-time: A-frags (main + mask) into registers ----
    short8 wA[NK][4];
    short8 mA[NK];
    #pragma unroll
    for (int kk = 0; kk < NK; kk++) {
        int k = KB + kk;
        const unsigned short* wp = Wf + (size_t)((k * 2 + ch) * 64) * 32 + quad * 8;
        #pragma unroll
        for (int s = 0; s < 4; s++)
            wA[kk][s] = *(const short8*)(wp + (s * 16 + n) * 32);
        mA[kk] = *(const short8*)(MWf + ((size_t)((k * 2 + ch) * 16 + n)) * 32 + quad * 8);
    }

    for (int tt = bid; tt < NTILES; tt += GRID) {
        int b, tl; unswz16(tt, &b, &tl);
        int p0 = tl * TPX;
        int p = p0 + n;
        int h = p / WW, wc = p % WW;
        const unsigned short* xTb = xT + (size_t)b * HW * 64;
        int cbase = ch * 32 + quad * 8;

        // ---- phase A: mask-conv partials (register A-frags) ----
        {
            float4v macc = {0.f, 0.f, 0.f, 0.f};
            #pragma unroll
            for (int kk = 0; kk < NK; kk++) {
                int q = KB + kk;
                int hh = h + q / 3 - 1, ww2 = wc + q % 3 - 1;
                bool valid = (hh >= 0) && (hh < HH) && (ww2 >= 0) && (ww2 < WW);
                int nidx = valid ? (hh * WW + ww2) : 0;
                short8 bfrag = {0, 0, 0, 0, 0, 0, 0, 0};
                if (valid) bfrag = *(const short8*)(xTb + (size_t)nidx * 64 + cbase);
                macc = __builtin_amdgcn_mfma_f32_16x16x32_bf16(mA[kk], bfrag, macc, 0, 0, 0);
            }
            #pragma unroll
            for (int r = 0; r < 4; r++) {
                int row = quad * 4 + r;
                if (row < 9) sm.mred[ch][tg][row][n] = macc[r];
            }
        }
        __syncthreads();

        // ---- phase B: sampling metadata (one thread per (tap,px)) ----
        if (t < K2 * TPX) {
            int k = t >> 4, pe = t & 15;
            int pp = p0 + pe;
            int hh0 = pp / WW, ww0 = pp % WW;
            int ky = k / 3, kx = k % 3;
            float oy = off[((size_t)b * 2 * K2 + 2 * k) * HW + pp];
            float ox = off[((size_t)b * 2 * K2 + 2 * k + 1) * HW + pp];
            float s = sm.mred[0][0][k][pe] + sm.mred[0][1][k][pe] +
                      sm.mred[1][0][k][pe] + sm.mred[1][1][k][pe] + mbias[k];
            float m = 1.f / (1.f + expf(-s));
            float py = (float)(hh0 - PADC + ky) + oy;
            float pxf = (float)(ww0 - PADC + kx) + ox;
            float y0f = floorf(py), x0f = floorf(pxf);
            float wy = py - y0f, wx = pxf - x0f;
            int y0 = (int)y0f, x0 = (int)x0f;
            int y1 = y0 + 1, x1 = x0 + 1;
            int y0c = min(max(y0, 0), HH - 1), y1c = min(max(y1, 0), HH - 1);
            int x0c = min(max(x0, 0), WW - 1), x1c = min(max(x1, 0), WW - 1);
            bool vy0 = (y0 >= 0) && (y0 < HH), vy1 = (y1 >= 0) && (y1 < HH);
            bool vx0 = (x0 >= 0) && (x0 < WW), vx1 = (x1 >= 0) && (x1 < WW);
            float w00 = (1.f - wy) * (1.f - wx) * m; if (!(vy0 && vx0)) w00 = 0.f;
            float w01 = (1.f - wy) * wx * m;         if (!(vy0 && vx1)) w01 = 0.f;
            float w10 = wy * (1.f - wx) * m;         if (!(vy1 && vx0)) w10 = 0.f;
            float w11 = wy * wx * m;                 if (!(vy1 && vx1)) w11 = 0.f;
            sm.idx[k][0][pe] = y0c * WW + x0c;
            sm.idx[k][1][pe] = y0c * WW + x1c;
            sm.idx[k][2][pe] = y1c * WW + x0c;
            sm.idx[k][3][pe] = y1c * WW + x1c;
            sm.w[k][0][pe] = w00; sm.w[k][1][pe] = w01;
            sm.w[k][2][pe] = w10; sm.w[k][3][pe] = w11;
        }
        __syncthreads();

        // ---- phase C: gather + blend + MFMA (register A-frags) ----
        float4v acc0 = {0.f, 0.f, 0.f, 0.f};
        float4v acc1 = {0.f, 0.f, 0.f, 0.f};
        float4v acc2 = {0.f, 0.f, 0.f, 0.f};
        float4v acc3 = {0.f, 0.f, 0.f, 0.f};
        const unsigned short* xq = xTb + cbase;

        #pragma unroll
        for (int kk = 0; kk < NK; kk++) {
            int k = KB + kk;
            int i0 = sm.idx[k][0][n], i1 = sm.idx[k][1][n];
            int i2 = sm.idx[k][2][n], i3 = sm.idx[k][3][n];
            float w0 = sm.w[k][0][n], w1 = sm.w[k][1][n];
            float w2 = sm.w[k][2][n], w3 = sm.w[k][3][n];
            short8 u0 = *(const short8*)(xq + (size_t)i0 * 64);
            short8 u1 = *(const short8*)(xq + (size_t)i1 * 64);
            short8 u2 = *(const short8*)(xq + (size_t)i2 * 64);
            short8 u3 = *(const short8*)(xq + (size_t)i3 * 64);
            short8 bfrag;
            #pragma unroll
            for (int j = 0; j < 8; j++) {
                float v = bf2f(u0[j]) * w0 + bf2f(u1[j]) * w1 +
                          bf2f(u2[j]) * w2 + bf2f(u3[j]) * w3;
                bfrag[j] = f2bf(v);
            }
            acc0 = __builtin_amdgcn_mfma_f32_16x16x32_bf16(wA[kk][0], bfrag, acc0, 0, 0, 0);
            acc1 = __builtin_amdgcn_mfma_f32_16x16x32_bf16(wA[kk][1], bfrag, acc1, 0, 0, 0);
            acc2 = __builtin_amdgcn_mfma_f32_16x16x32_bf16(wA[kk][2], bfrag, acc2, 0, 0, 0);
            acc3 = __builtin_amdgcn_mfma_f32_16x16x32_bf16(wA[kk][3], bfrag, acc3, 0, 0, 0);
        }

        // ---- cross-wave reduce (4 partials) + epilogue ----
        if (wv != 0) {
            #pragma unroll
            for (int r = 0; r < 4; r++) {
                sm.part[wv - 1][0 * 4 + r][lane] = acc0[r];
                sm.part[wv - 1][1 * 4 + r][lane] = acc1[r];
                sm.part[wv - 1][2 * 4 + r][lane] = acc2[r];
                sm.part[wv - 1][3 * 4 + r][lane] = acc3[r];
            }
        }
        __syncthreads();
        if (wv == 0) {
            float* ob = out + (size_t)b * CO * HW + p0 + n;
            #pragma unroll
            for (int r = 0; r < 4; r++) {
                int j0 = r, j1 = 4 + r, j2 = 8 + r, j3 = 12 + r;
                ob[(size_t)(0 * 16 + quad * 4 + r) * HW] =
                    acc0[r] + sm.part[0][j0][lane] + sm.part[1][j0][lane] + sm.part[2][j0][lane];
                ob[(size_t)(1 * 16 + quad * 4 + r) * HW] =
                    acc1[r] + sm.part[0][j1][lane] + sm.part[1][j1][lane] + sm.part[2][j1][lane];
                ob[(size_t)(2 * 16 + quad * 4 + r) * HW] =
                    acc2[r] + sm.part[0][j2][lane] + sm.part[1][j2][lane] + sm.part[2][j2][lane];
                ob[(size_t)(3 * 16 + quad * 4 + r) * HW] =
                    acc3[r] + sm.part[0][j3][lane] + sm.part[1][j3][lane] + sm.part[2][j3][lane];
            }
        }
    }
}

__global__ __launch_bounds__(256, 2) void fused_kernel(const float* __restrict__ off,
                                                       const float* __restrict__ mbias,
                                                       const unsigned short* __restrict__ xT,
                                                       const unsigned short* __restrict__ Wf,
                                                       const unsigned short* __restrict__ MWf,
                                                       float* __restrict__ out) {
    __shared__ SmemT sm;
    int t = threadIdx.x;
    int lane = t & 63, wv = t >> 6;
    int ch = wv & 1, tg = wv >> 1;
    int n = lane & 15, quad = lane >> 4;
    if (tg == 0)
        tile_work<0, 5>(sm, t, wv, ch, tg, n, quad, off, mbias, xT, Wf, MWf, out, blockIdx.x);
    else
        tile_work<5, 9>(sm, t, wv, ch, tg, n, quad, off, mbias, xT, Wf, MWf, out, blockIdx.x);
}

extern "C" void kernel_launch(void* const* d_in, const int* in_sizes, int n_in,
                              void* d_out, int out_size, void* d_ws, size_t ws_size,
                              hipStream_t stream) {
    const float* x   = (const float*)d_in[0];
    const float* off = (const float*)d_in[1];
    const float* wgt = (const float*)d_in[2];
    const float* mw  = (const float*)d_in[3];
    const float* mb  = (const float*)d_in[4];
    float* out = (float*)d_out;

    unsigned short* xT  = (unsigned short*)d_ws;
    unsigned short* Wf  = xT + XT_USHORTS;
    unsigned short* MWf = Wf + WF_USHORTS;

    int prep_grid = PBASE + (WF_USHORTS + MWF_USHORTS + 255) / 256;   // 1152 + 360
    hipLaunchKernelGGL(prep_kernel, dim3(prep_grid), dim3(256), 0, stream,
                       x, wgt, mw, xT, Wf, MWf);
    hipLaunchKernelGGL(fused_kernel, dim3(GRID), dim3(256), 0, stream,
                       off, mb, xT, Wf, MWf, out);
}

// Round 8
// 101.227 us; speedup vs baseline: 1.0623x; 1.0229x over previous
//
#include <hip/hip_runtime.h>
#include <math.h>

#define BB 4
#define CI 64
#define CO 64
#define HH 96
#define WW 96
#define HW (HH*WW)      // 9216
#define K2 9
#define PADC 1

// fused tiling: 8x4-px tiles
#define TW 8
#define TH 4
#define TPXT (TW*TH)        // 32 px per tile
#define TBX (WW/TW)         // 12
#define TBY (HH/TH)         // 24
#define NTILB (TBX*TBY)     // 288 tiles per batch
#define NTILES (BB*NTILB)   // 1152

// LDS window: rows [h0-4, h0+TH+8], cols [w0-4, w0+15]
#define WR (TH+9)           // 13 rows
#define WC 20               // 20 cols (5 float4 chunks)
#define SREC 72             // ushorts per px record (144B: 128B data + 16B pad -> 2-way banks)
#define NSLOT (WR*WC)       // 260 slots

typedef __attribute__((ext_vector_type(8))) short short8;
typedef __attribute__((ext_vector_type(4))) float float4v;

// ws layout: Wf (18*64*32 ushort) + MWf (18*16*32 ushort)
#define WF_USHORTS (18*64*32)
#define MWF_USHORTS (18*16*32)

__device__ __forceinline__ float bf2f(short s) {
    return __uint_as_float(((unsigned int)(unsigned short)s) << 16);
}
__device__ __forceinline__ short f2bf(float f) {
    unsigned int u = __float_as_uint(f);
    u = (u + 0x7fffu + ((u >> 16) & 1u)) >> 16;   // RNE
    return (short)u;
}

// XCD swizzle: XCD g serves only batch g&3 so its 4MB L2 caches that batch's
// x slice (2.36MB fp32). [R3: FETCH 15->4MB verified with same scheme]
__device__ __forceinline__ void unswz(int bid, int* b, int* ty, int* tx) {
    int g = bid & 7, r = bid >> 3;      // r in [0,144)
    *b = g & 3;
    int tile = (g >> 2) * 144 + r;      // [0,288)
    *ty = tile / TBX; *tx = tile % TBX;
}

// ---------------- prep: weight pack only (xT eliminated) ----------------
__global__ __launch_bounds__(256) void pack_kernel(const float* __restrict__ wgt,
                                                   const float* __restrict__ mw,
                                                   unsigned short* __restrict__ Wf,
                                                   unsigned short* __restrict__ MWf) {
    int i = blockIdx.x * 256 + threadIdx.x;
    if (i < WF_USHORTS) {
        int frag = i >> 11;
        int o = (i >> 5) & 63;
        int tt = i & 31;
        int k = frag >> 1, cc = frag & 1;
        int c = cc * 32 + tt;
        Wf[i] = (unsigned short)f2bf(wgt[o * 576 + c * 9 + k]);
    } else if (i < WF_USHORTS + MWF_USHORTS) {
        int e = i - WF_USHORTS;
        int frag = e >> 9;
        int m = (e >> 5) & 15;
        int tt = e & 31;
        int q = frag >> 1, cc = frag & 1;
        int c = cc * 32 + tt;
        MWf[e] = (m < 9) ? (unsigned short)f2bf(mw[m * 576 + c * 9 + q]) : 0;
    }
}

// ---------------- fused: LDS-window staged mask conv + deform + GEMM ----------
// Block = 4 waves over one 8x4 tile: wave (pg = wv>>1: px-group of 16,
// ch = wv&1: 32-channel half). Gathers hit the LDS window; rare out-of-window
// corners (|offset| > ~3) fall back to exec-masked global reads of x.
__global__ __launch_bounds__(256, 3) void fused_kernel(const float* __restrict__ x,
                                                       const float* __restrict__ off,
                                                       const float* __restrict__ mbias,
                                                       const unsigned short* __restrict__ Wf,
                                                       const unsigned short* __restrict__ MWf,
                                                       float* __restrict__ out) {
    __shared__ __align__(16) unsigned short win[NSLOT * SREC];   // 37,440 B
    __shared__ float s_mred[2][K2][TPXT];                        // 2,304 B
    __shared__ int   s_idx[K2][4][TPXT];                         // 4,608 B
    __shared__ float s_w[K2][4][TPXT];                           // 4,608 B
    float* part = (float*)win;   // [2][16][64] aliased AFTER window is dead

    int t = threadIdx.x;
    int lane = t & 63, wv = t >> 6;
    int pg = wv >> 1, ch = wv & 1;
    int n = lane & 15, quad = lane >> 4;
    int b, ty, tx; unswz(blockIdx.x, &b, &ty, &tx);
    int h0 = ty * TH, w0 = tx * TW;
    int wr0 = h0 - 4, wc0 = w0 - 4;
    const float* xb = x + (size_t)b * CI * HW;

    // ---- stage window: fp32 x -> bf16 LDS records, transposed on the fly ----
    // task e = (r, chp, c4): row r, channel-pair 2chp, col-chunk of 4
    for (int e = t; e < WR * 32 * 5; e += 256) {
        int r = e / 160, rem = e % 160, chp = rem / 5, c4 = rem % 5;
        int row = min(max(wr0 + r, 0), HH - 1);
        int c0c = wc0 + c4 * 4;
        const float* s0 = xb + (size_t)(2 * chp) * HW + row * WW;
        const float* s1 = s0 + HW;
        float v0[4], v1[4];
        if (c0c >= 0 && c0c + 3 < WW) {
            float4v a = *(const float4v*)(s0 + c0c);
            float4v bq = *(const float4v*)(s1 + c0c);
            v0[0]=a[0]; v0[1]=a[1]; v0[2]=a[2]; v0[3]=a[3];
            v1[0]=bq[0]; v1[1]=bq[1]; v1[2]=bq[2]; v1[3]=bq[3];
        } else {
            #pragma unroll
            for (int j = 0; j < 4; j++) {
                int cc2 = min(max(c0c + j, 0), WW - 1);
                v0[j] = s0[cc2]; v1[j] = s1[cc2];
            }
        }
        #pragma unroll
        for (int j = 0; j < 4; j++) {
            unsigned int pk = (unsigned short)f2bf(v0[j]) |
                              ((unsigned int)(unsigned short)f2bf(v1[j]) << 16);
            *(unsigned int*)&win[(r * WC + c4 * 4 + j) * SREC + 2 * chp] = pk;
        }
    }
    __syncthreads();

    int pxl = pg * 16 + n;                 // px within tile
    int ly = pxl >> 3, lx = pxl & 7;
    int h = h0 + ly, wcc = w0 + lx;
    int cbase_us = ch * 32 + quad * 8;     // ushort offset within record

    // ---- phase A: mask-conv partials via MFMA, B-frags from LDS window ----
    {
        float4v macc = {0.f, 0.f, 0.f, 0.f};
        #pragma unroll
        for (int q = 0; q < 9; q++) {
            int hh = h + q / 3 - 1, ww2 = wcc + q % 3 - 1;
            bool valid = (hh >= 0) && (hh < HH) && (ww2 >= 0) && (ww2 < WW);
            short8 bfrag = {0, 0, 0, 0, 0, 0, 0, 0};
            if (valid) {
                int slot = (hh - wr0) * WC + (ww2 - wc0);   // always in window
                bfrag = *(const short8*)&win[slot * SREC + cbase_us];
            }
            short8 afrag = *(const short8*)(MWf + ((size_t)((q * 2 + ch) * 16 + n)) * 32 + quad * 8);
            macc = __builtin_amdgcn_mfma_f32_16x16x32_bf16(afrag, bfrag, macc, 0, 0, 0);
        }
        #pragma unroll
        for (int r = 0; r < 4; r++) {
            int row = quad * 4 + r;
            if (row < 9) s_mred[ch][row][pxl] = macc[r];
        }
    }
    __syncthreads();

    // ---- phase B: sampling metadata (corner coords packed, mask folded) ----
    for (int e = t; e < K2 * TPXT; e += 256) {
        int k = e >> 5, pe = e & 31;
        int ph = h0 + (pe >> 3), pw = w0 + (pe & 7);
        int p = ph * WW + pw;
        float oy = off[((size_t)b * 2 * K2 + 2 * k) * HW + p];
        float ox = off[((size_t)b * 2 * K2 + 2 * k + 1) * HW + p];
        float s = s_mred[0][k][pe] + s_mred[1][k][pe] + mbias[k];
        float m = 1.f / (1.f + expf(-s));
        float py  = (float)(ph - PADC + k / 3) + oy;
        float pxf = (float)(pw - PADC + k % 3) + ox;
        float y0f = floorf(py), x0f = floorf(pxf);
        float wy = py - y0f, wx = pxf - x0f;
        int y0 = (int)y0f, x0 = (int)x0f;
        int y1 = y0 + 1, x1 = x0 + 1;
        int y0c = min(max(y0, 0), HH - 1), y1c = min(max(y1, 0), HH - 1);
        int x0c = min(max(x0, 0), WW - 1), x1c = min(max(x1, 0), WW - 1);
        bool vy0 = (y0 >= 0) && (y0 < HH), vy1 = (y1 >= 0) && (y1 < HH);
        bool vx0 = (x0 >= 0) && (x0 < WW), vx1 = (x1 >= 0) && (x1 < WW);
        float w00 = (1.f - wy) * (1.f - wx) * m; if (!(vy0 && vx0)) w00 = 0.f;
        float w01 = (1.f - wy) * wx * m;         if (!(vy0 && vx1)) w01 = 0.f;
        float w10 = wy * (1.f - wx) * m;         if (!(vy1 && vx0)) w10 = 0.f;
        float w11 = wy * wx * m;                 if (!(vy1 && vx1)) w11 = 0.f;
        s_idx[k][0][pe] = (y0c << 16) | x0c;
        s_idx[k][1][pe] = (y0c << 16) | x1c;
        s_idx[k][2][pe] = (y1c << 16) | x0c;
        s_idx[k][3][pe] = (y1c << 16) | x1c;
        s_w[k][0][pe] = w00; s_w[k][1][pe] = w01;
        s_w[k][2][pe] = w10; s_w[k][3][pe] = w11;
    }
    __syncthreads();

    // ---- phase C: gather from LDS window (global fallback) + blend + MFMA ----
    float4v acc0 = {0.f, 0.f, 0.f, 0.f};
    float4v acc1 = {0.f, 0.f, 0.f, 0.f};
    float4v acc2 = {0.f, 0.f, 0.f, 0.f};
    float4v acc3 = {0.f, 0.f, 0.f, 0.f};
    const float* xfb = xb + (size_t)(ch * 32 + quad * 8) * HW;   // fallback channel base

    #pragma unroll
    for (int k = 0; k < 9; k++) {
        short8 U[4];
        #pragma unroll
        for (int cor = 0; cor < 4; cor++) {
            int yx = s_idx[k][cor][pxl];
            int yy = yx >> 16, xx = yx & 0xffff;
            int r = yy - wr0, c = xx - wc0;
            bool inw = ((unsigned)r < (unsigned)WR) && ((unsigned)c < (unsigned)WC);
            short8 u;
            if (inw) {
                u = *(const short8*)&win[(r * WC + c) * SREC + cbase_us];
            } else {
                const float* fs = xfb + yy * WW + xx;
                #pragma unroll
                for (int j = 0; j < 8; j++) u[j] = f2bf(fs[(size_t)j * HW]);
            }
            U[cor] = u;
        }
        float w0 = s_w[k][0][pxl], w1 = s_w[k][1][pxl];
        float w2 = s_w[k][2][pxl], w3 = s_w[k][3][pxl];
        short8 bfrag;
        #pragma unroll
        for (int j = 0; j < 8; j++) {
            float v = bf2f(U[0][j]) * w0 + bf2f(U[1][j]) * w1 +
                      bf2f(U[2][j]) * w2 + bf2f(U[3][j]) * w3;
            bfrag[j] = f2bf(v);
        }
        const unsigned short* wp = Wf + (size_t)((k * 2 + ch) * 64) * 32 + quad * 8;
        short8 a0 = *(const short8*)(wp + (0 * 16 + n) * 32);
        short8 a1 = *(const short8*)(wp + (1 * 16 + n) * 32);
        short8 a2 = *(const short8*)(wp + (2 * 16 + n) * 32);
        short8 a3 = *(const short8*)(wp + (3 * 16 + n) * 32);
        acc0 = __builtin_amdgcn_mfma_f32_16x16x32_bf16(a0, bfrag, acc0, 0, 0, 0);
        acc1 = __builtin_amdgcn_mfma_f32_16x16x32_bf16(a1, bfrag, acc1, 0, 0, 0);
        acc2 = __builtin_amdgcn_mfma_f32_16x16x32_bf16(a2, bfrag, acc2, 0, 0, 0);
        acc3 = __builtin_amdgcn_mfma_f32_16x16x32_bf16(a3, bfrag, acc3, 0, 0, 0);
    }

    // ---- cross-wave ch-reduce via part (aliases dead window) + epilogue ----
    __syncthreads();   // all window reads complete before alias write
    if (ch == 1) {
        #pragma unroll
        for (int r = 0; r < 4; r++) {
            part[(pg * 16 + 0 * 4 + r) * 64 + lane] = acc0[r];
            part[(pg * 16 + 1 * 4 + r) * 64 + lane] = acc1[r];
            part[(pg * 16 + 2 * 4 + r) * 64 + lane] = acc2[r];
            part[(pg * 16 + 3 * 4 + r) * 64 + lane] = acc3[r];
        }
    }
    __syncthreads();
    if (ch == 0) {
        float* ob = out + (size_t)b * CO * HW + h * WW + wcc;
        #pragma unroll
        for (int r = 0; r < 4; r++) {
            ob[(size_t)(0 * 16 + quad * 4 + r) * HW] =
                acc0[r] + part[(pg * 16 + 0 * 4 + r) * 64 + lane];
            ob[(size_t)(1 * 16 + quad * 4 + r) * HW] =
                acc1[r] + part[(pg * 16 + 1 * 4 + r) * 64 + lane];
            ob[(size_t)(2 * 16 + quad * 4 + r) * HW] =
                acc2[r] + part[(pg * 16 + 2 * 4 + r) * 64 + lane];
            ob[(size_t)(3 * 16 + quad * 4 + r) * HW] =
                acc3[r] + part[(pg * 16 + 3 * 4 + r) * 64 + lane];
        }
    }
}

extern "C" void kernel_launch(void* const* d_in, const int* in_sizes, int n_in,
                              void* d_out, int out_size, void* d_ws, size_t ws_size,
                              hipStream_t stream) {
    const float* x   = (const float*)d_in[0];
    const float* off = (const float*)d_in[1];
    const float* wgt = (const float*)d_in[2];
    const float* mw  = (const float*)d_in[3];
    const float* mb  = (const float*)d_in[4];
    float* out = (float*)d_out;

    unsigned short* Wf  = (unsigned short*)d_ws;
    unsigned short* MWf = Wf + WF_USHORTS;

    hipLaunchKernelGGL(pack_kernel, dim3((WF_USHORTS + MWF_USHORTS + 255) / 256), dim3(256),
                       0, stream, wgt, mw, Wf, MWf);
    hipLaunchKernelGGL(fused_kernel, dim3(NTILES), dim3(256), 0, stream,
                       x, off, mb, Wf, MWf, out);
}